// Round 8
// baseline (1019.310 us; speedup 1.0000x reference)
//
#include <hip/hip_runtime.h>

// GlobalDistNet forward, round 8:
//  - aggs: 2 rows per load instruction (32 lanes x f16x4 per row), pair-unroll-4
//    = 8 rows in flight; halves merged via shfl_xor(32)
//  - residual fused into the NEXT lin GEMM's A-staging (reads x fp32 + y f16 +
//    scale/shift, writes updated x); final residual fused into k_dot1;
//    y stored f16; xh buffer deleted; 8 fewer launches
//  - embed GEMM unchanged (at its gather-traffic floor ~110MB @ ~1TB/s)

typedef _Float16 f16;
typedef f16 f16x8 __attribute__((ext_vector_type(8)));
typedef f16 f16x4 __attribute__((ext_vector_type(4)));
typedef f16 f16x2 __attribute__((ext_vector_type(2)));
typedef float f32x4 __attribute__((ext_vector_type(4)));

__device__ __forceinline__ float lrelu(float x, float s){ return x>=0.f? x : s*x; }

// ---------------- CSR build ----------------
__global__ __launch_bounds__(256) void k_deg(const int* __restrict__ dst,
                                             int* __restrict__ deg, int E) {
  int i = blockIdx.x * 256 + threadIdx.x;
  if (i < E) atomicAdd(&deg[dst[i]], 1);
}

__global__ __launch_bounds__(1024) void k_scan1(const int* __restrict__ deg,
    int* __restrict__ row_ptr, int* __restrict__ bsum, float* __restrict__ dinv, int n) {
  int b = blockIdx.x, t = threadIdx.x, i = b * 1024 + t;
  __shared__ int sd[1024];
  int v = (i < n) ? deg[i] : 0;
  if (i < n) dinv[i] = rsqrtf((float)(v + 1));
  sd[t] = v;
  __syncthreads();
  for (int off = 1; off < 1024; off <<= 1) {
    int o = (t >= off) ? sd[t - off] : 0;
    __syncthreads();
    sd[t] += o;
    __syncthreads();
  }
  if (i < n) row_ptr[i + 1] = sd[t];
  if (t == 1023) bsum[b] = sd[1023];
  if (b == 0 && t == 0) row_ptr[0] = 0;
}

__global__ __launch_bounds__(64) void k_scan2(int* __restrict__ bsum, int nb) {
  int lane = threadIdx.x;
  int v = (lane < nb) ? bsum[lane] : 0;
  int x = v;
  for (int off = 1; off < 64; off <<= 1) {
    int o = __shfl_up(x, off, 64);
    if (lane >= off) x += o;
  }
  if (lane < nb) bsum[lane] = x - v;
}

__global__ __launch_bounds__(256) void k_scan3(int* __restrict__ row_ptr,
                                               const int* __restrict__ bsum, int n) {
  int i = blockIdx.x * 256 + threadIdx.x;
  if (i < n) row_ptr[i + 1] += bsum[i >> 10];
}

__global__ __launch_bounds__(256) void k_fill(const int* __restrict__ src,
                                              const int* __restrict__ dst,
                                              const int* __restrict__ row_ptr,
                                              const float* __restrict__ dinv,
                                              int* __restrict__ fill,
                                              int* __restrict__ csr,
                                              float* __restrict__ csrw, int E) {
  int i = blockIdx.x * 256 + threadIdx.x;
  if (i < E) {
    int d = dst[i], s = src[i];
    int pos = row_ptr[d] + atomicAdd(&fill[d], 1);
    csr[pos] = s;
    csrw[pos] = dinv[d] * dinv[s];
  }
}

// ---------------- conversions / packing ----------------
__global__ __launch_bounds__(256) void k_conv_emb(const float* __restrict__ src,
                                                  f16* __restrict__ dst, int total4) {
  int i = blockIdx.x * 256 + threadIdx.x;
  if (i >= total4) return;
  float4 v = ((const float4*)src)[i];
  f16x4 o = { (f16)v.x, (f16)v.y, (f16)v.z, (f16)v.w };
  ((f16x4*)dst)[i] = o;
}

__global__ __launch_bounds__(256) void k_pack_w(const float* __restrict__ W,
    f16* __restrict__ hi, int kb_total) {
  int idx = blockIdx.x * 256 + threadIdx.x;
  int c = idx & 127, kb = idx >> 7;
  if (kb >= kb_total) return;
  f16x8 hv;
#pragma unroll
  for (int j = 0; j < 8; j++) hv[j] = (f16)W[(size_t)(kb*8 + j) * 128 + c];
  ((f16x8*)hi)[idx] = hv;
}

__global__ __launch_bounds__(256) void k_pack_w8(const float* __restrict__ gcnW,
    const float* __restrict__ gatW, f16* __restrict__ hi, f16* __restrict__ lo) {
  int mat = blockIdx.y;
  const float* W = (mat < 4) ? gcnW + (size_t)mat * 16384 : gatW + (size_t)(mat - 4) * 16384;
  int idx = blockIdx.x * 256 + threadIdx.x;
  int c = idx & 127, kb = idx >> 7;
  f16x8 hv, lv;
#pragma unroll
  for (int j = 0; j < 8; j++) {
    float v = W[(size_t)(kb*8 + j) * 128 + c];
    f16 h = (f16)v;
    hv[j] = h; lv[j] = (f16)(v - (float)h);
  }
  ((f16x8*)hi)[mat * 2048 + idx] = hv;
  ((f16x8*)lo)[mat * 2048 + idx] = lv;
}

// ---------------- MFMA GEMM: embed-gather A, K=4128, dual K-half block ------------
#define APAD 152
__global__ __launch_bounds__(512) void k_mfma_embed(const int* __restrict__ poi,
    const float* __restrict__ dist, const f16* __restrict__ eh,
    const f16* __restrict__ wh, f16* __restrict__ H16, int n) {
  __shared__ __attribute__((aligned(16))) char smem[49152];
  int* poi_s = (int*)smem;
  f16* aS    = (f16*)(smem + 8192);
  f16* OT    = (f16*)smem;
  float* F   = (float*)(smem + 16384);
  int tid = threadIdx.x;
  int bn = blockIdx.x * 64;
  int half = tid >> 8;
  int t2 = tid & 255;
  int ln = t2 >> 2, qt = t2 & 3;
  int xrow = bn + ln; if (xrow > n - 1) xrow = n - 1;
  {
#pragma unroll
    for (int jj = 0; jj < 4; jj++)
      poi_s[half * 1024 + (qt * 4 + jj) * 64 + ln] =
        poi[(size_t)xrow * 32 + half * 16 + qt * 4 + jj];
  }
  int w2 = (tid >> 6) & 3, lane = tid & 63;
  int q = lane >> 4, l15 = lane & 15;
  int mtb = (w2 & 1) * 2;
  int ntb = (w2 >> 1) * 4;
  f16* aH = aS + half * 64 * APAD;
  f32x4 acc[2][4];
#pragma unroll
  for (int a = 0; a < 2; a++)
#pragma unroll
    for (int b = 0; b < 4; b++) { acc[a][b][0]=0.f; acc[a][b][1]=0.f; acc[a][b][2]=0.f; acc[a][b][3]=0.f; }
  __syncthreads();

  f16x8 r0, r1, r2, r3;
  {
    const f16* srcp = eh + (size_t)poi_s[half * 1024 + ln] * 128 + qt * 32;
    r0 = *(const f16x8*)(srcp);      r1 = *(const f16x8*)(srcp + 8);
    r2 = *(const f16x8*)(srcp + 16); r3 = *(const f16x8*)(srcp + 24);
  }

#pragma unroll 1
  for (int j = 0; j < 16; j++) {
    __syncthreads();
    f16* wp = aH + ln * APAD + qt * 32;
    *(f16x8*)(wp) = r0; *(f16x8*)(wp + 8) = r1;
    *(f16x8*)(wp + 16) = r2; *(f16x8*)(wp + 24) = r3;
    if (j + 1 < 16) {
      const f16* srcp = eh + (size_t)poi_s[half * 1024 + (j + 1) * 64 + ln] * 128 + qt * 32;
      r0 = *(const f16x8*)(srcp);      r1 = *(const f16x8*)(srcp + 8);
      r2 = *(const f16x8*)(srcp + 16); r3 = *(const f16x8*)(srcp + 24);
    }
    __syncthreads();
#pragma unroll
    for (int kcl = 0; kcl < 4; kcl++) {
      f16x8 a_h[2];
#pragma unroll
      for (int mi = 0; mi < 2; mi++)
        a_h[mi] = *(const f16x8*)(aH + ((mtb + mi) * 16 + l15) * APAD + kcl * 32 + q * 8);
      int kb = (half * 16 + j) * 16 + kcl * 4 + q;
#pragma unroll
      for (int ni = 0; ni < 4; ni++) {
        f16x8 bh = *(const f16x8*)(wh + ((size_t)kb * 128 + (ntb + ni) * 16 + l15) * 8);
#pragma unroll
        for (int mi = 0; mi < 2; mi++)
          acc[mi][ni] = __builtin_amdgcn_mfma_f32_16x16x32_f16(a_h[mi], bh, acc[mi][ni], 0, 0, 0);
      }
    }
  }
  if (half) {
    int nc0 = bn + (mtb + 0) * 16 + l15; if (nc0 > n - 1) nc0 = n - 1;
    int nc1 = bn + (mtb + 1) * 16 + l15; if (nc1 > n - 1) nc1 = n - 1;
    f16x8 ad[2];
#pragma unroll
    for (int mi = 0; mi < 2; mi++) {
      int nc = mi ? nc1 : nc0;
      const float* dp = dist + (size_t)nc * 32 + q * 8;
      float4 d0 = *(const float4*)dp, d1 = *(const float4*)(dp + 4);
      ad[mi][0]=(f16)d0.x; ad[mi][1]=(f16)d0.y; ad[mi][2]=(f16)d0.z; ad[mi][3]=(f16)d0.w;
      ad[mi][4]=(f16)d1.x; ad[mi][5]=(f16)d1.y; ad[mi][6]=(f16)d1.z; ad[mi][7]=(f16)d1.w;
    }
    int kb = 512 + q;
#pragma unroll
    for (int ni = 0; ni < 4; ni++) {
      f16x8 bh = *(const f16x8*)(wh + ((size_t)kb * 128 + (ntb + ni) * 16 + l15) * 8);
#pragma unroll
      for (int mi = 0; mi < 2; mi++)
        acc[mi][ni] = __builtin_amdgcn_mfma_f32_16x16x32_f16(ad[mi], bh, acc[mi][ni], 0, 0, 0);
    }
  }
  __syncthreads();
  if (half) {
#pragma unroll
    for (int mi = 0; mi < 2; mi++)
#pragma unroll
      for (int ni = 0; ni < 4; ni++)
#pragma unroll
        for (int r = 0; r < 4; r++)
          F[((mtb + mi) * 16 + q * 4 + r) * 128 + (ntb + ni) * 16 + l15] = acc[mi][ni][r];
  }
  __syncthreads();
  if (!half) {
#pragma unroll
    for (int mi = 0; mi < 2; mi++)
#pragma unroll
      for (int ni = 0; ni < 4; ni++)
#pragma unroll
        for (int r = 0; r < 4; r++) {
          int o = ((mtb + mi) * 16 + q * 4 + r) * 128 + (ntb + ni) * 16 + l15;
          OT[o] = (f16)(acc[mi][ni][r] + F[o]);
        }
  }
  __syncthreads();
#pragma unroll
  for (int ch = 0; ch < 2; ch++) {
    int c1024 = tid + ch * 512;
    int row = c1024 >> 4, c8 = c1024 & 15;
    if (bn + row < n)
      *(f16x8*)(H16 + (size_t)(bn + row) * 128 + c8 * 8) = *(const f16x8*)(OT + row * 128 + c8 * 8);
  }
}

// ---------------- MFMA GEMM: A from x (+fused residual), K=128 -------------------
// If Y!=null: xnew = x + lrelu(scale*y+shift); x written back; A = f16(xnew).
// If asrc!=null: fused GAT a-dot epilogue -> als/ald.
#define LPAD 136
__global__ __launch_bounds__(256) void k_mfma_lin(float* __restrict__ X,
    const f16* __restrict__ Y, const float* __restrict__ scaleA,
    const float* __restrict__ shiftA,
    const f16* __restrict__ wh, const f16* __restrict__ wl,
    f16* __restrict__ H16, int n,
    const float* __restrict__ asrc, const float* __restrict__ adst,
    float* __restrict__ als, float* __restrict__ ald) {
  __shared__ __attribute__((aligned(16))) char smem[64 * LPAD * 2];
  f16* aS = (f16*)smem;
  f16* ot = (f16*)smem;
  float* dsrc = (float*)(smem + 16384);
  float* ddst = (float*)(smem + 16896);
  int tid = threadIdx.x;
  int bn = blockIdx.x * 64;
  int ln = tid >> 2, qt = tid & 3;
  int xrow = bn + ln; bool valid = xrow < n; if (!valid) xrow = n - 1;
  int w = tid >> 6, lane = tid & 63;
  int q = lane >> 4, l15 = lane & 15;
  int mtb = (w & 1) * 2;
  int ntb = (w >> 1) * 4;
  {
    float* xp = X + (size_t)xrow * 128 + qt * 32;
    f16* wp = aS + ln * LPAD + qt * 32;
    if (Y) {
      const f16* yp = Y + (size_t)xrow * 128 + qt * 32;
#pragma unroll
      for (int cc = 0; cc < 32; cc += 4) {
        float4 xv = *(const float4*)(xp + cc);
        f16x4 yv = *(const f16x4*)(yp + cc);
        float4 sc = *(const float4*)(scaleA + qt * 32 + cc);
        float4 sh = *(const float4*)(shiftA + qt * 32 + cc);
        xv.x += lrelu(sc.x * (float)yv[0] + sh.x, 0.01f);
        xv.y += lrelu(sc.y * (float)yv[1] + sh.y, 0.01f);
        xv.z += lrelu(sc.z * (float)yv[2] + sh.z, 0.01f);
        xv.w += lrelu(sc.w * (float)yv[3] + sh.w, 0.01f);
        if (valid) *(float4*)(xp + cc) = xv;
        f16x4 st = { (f16)xv.x, (f16)xv.y, (f16)xv.z, (f16)xv.w };
        *(f16x4*)(wp + cc) = st;
      }
    } else {
#pragma unroll
      for (int cc = 0; cc < 32; cc += 4) {
        float4 xv = *(const float4*)(xp + cc);
        f16x4 st = { (f16)xv.x, (f16)xv.y, (f16)xv.z, (f16)xv.w };
        *(f16x4*)(wp + cc) = st;
      }
    }
  }
  float av[4], bv[4];
  if (asrc) {
#pragma unroll
    for (int ni = 0; ni < 4; ni++) {
      av[ni] = asrc[(ntb + ni) * 16 + l15];
      bv[ni] = adst[(ntb + ni) * 16 + l15];
    }
  }
  f32x4 acc[2][4];
#pragma unroll
  for (int a = 0; a < 2; a++)
#pragma unroll
    for (int b = 0; b < 4; b++) { acc[a][b][0]=0.f; acc[a][b][1]=0.f; acc[a][b][2]=0.f; acc[a][b][3]=0.f; }
  __syncthreads();
#pragma unroll
  for (int kcl = 0; kcl < 4; kcl++) {
    f16x8 a_h[2];
#pragma unroll
    for (int mi = 0; mi < 2; mi++)
      a_h[mi] = *(const f16x8*)(aS + ((mtb + mi) * 16 + l15) * LPAD + kcl * 32 + q * 8);
    int kb = kcl * 4 + q;
#pragma unroll
    for (int ni = 0; ni < 4; ni++) {
      size_t boff = ((size_t)kb * 128 + (ntb + ni) * 16 + l15) * 8;
      f16x8 bh = *(const f16x8*)(wh + boff);
      f16x8 bl = *(const f16x8*)(wl + boff);
#pragma unroll
      for (int mi = 0; mi < 2; mi++) {
        acc[mi][ni] = __builtin_amdgcn_mfma_f32_16x16x32_f16(a_h[mi], bh, acc[mi][ni], 0, 0, 0);
        acc[mi][ni] = __builtin_amdgcn_mfma_f32_16x16x32_f16(a_h[mi], bl, acc[mi][ni], 0, 0, 0);
      }
    }
  }
  __syncthreads();
  if (asrc) {
#pragma unroll
    for (int mi = 0; mi < 2; mi++)
#pragma unroll
      for (int r = 0; r < 4; r++) {
        float ps = 0.f, pd = 0.f;
#pragma unroll
        for (int ni = 0; ni < 4; ni++) { ps += acc[mi][ni][r] * av[ni]; pd += acc[mi][ni][r] * bv[ni]; }
#pragma unroll
        for (int msk = 8; msk > 0; msk >>= 1) {
          ps += __shfl_xor(ps, msk, 64);
          pd += __shfl_xor(pd, msk, 64);
        }
        if (l15 == 0) {
          int row = (mtb + mi) * 16 + q * 4 + r;
          dsrc[row * 2 + (w >> 1)] = ps;
          ddst[row * 2 + (w >> 1)] = pd;
        }
      }
  }
#pragma unroll
  for (int mi = 0; mi < 2; mi++)
#pragma unroll
    for (int ni = 0; ni < 4; ni++)
#pragma unroll
      for (int r = 0; r < 4; r++)
        ot[((mtb + mi) * 16 + q * 4 + r) * 128 + (ntb + ni) * 16 + l15] = (f16)acc[mi][ni][r];
  __syncthreads();
  if (bn + ln < n) {
    f16* dst = H16 + (size_t)(bn + ln) * 128 + qt * 32;
    const f16* srcp = ot + ln * 128 + qt * 32;
#pragma unroll
    for (int jj = 0; jj < 4; jj++)
      *(f16x8*)(dst + jj * 8) = *(const f16x8*)(srcp + jj * 8);
  }
  if (asrc && tid < 64 && bn + tid < n) {
    als[bn + tid] = dsrc[tid * 2] + dsrc[tid * 2 + 1];
    ald[bn + tid] = ddst[tid * 2] + ddst[tid * 2 + 1];
  }
}

// ---------------- GCN aggregation: 2 rows/instr, pair-unroll-4 ----------------
__global__ __launch_bounds__(256) void k_gcn_agg16(const f16x4* __restrict__ H4,
    const float* __restrict__ dinv, const int* __restrict__ row_ptr,
    const int* __restrict__ csr, const float* __restrict__ csrw,
    const float* __restrict__ bias,
    float4* __restrict__ xout4, f16x4* __restrict__ y4, int n, int leaky_flag,
    float* __restrict__ psum, float* __restrict__ psumsq) {
  int w = threadIdx.x >> 6;
  int node = blockIdx.x * 4 + w;
  int lane = threadIdx.x & 63;
  int half = lane >> 5, li = lane & 31;
  __shared__ float s1[4][128], s2[4][128];
  float o0=0.f,o1=0.f,o2=0.f,o3=0.f;
  if (node < n) {
    int rs = row_ptr[node], re = row_ptr[node + 1];
    int d = re - rs;
    float dn = dinv[node];
    int  sidx = (lane < d) ? csr[rs + lane]  : 0;
    float swt = (lane < d) ? csrw[rs + lane] : 0.f;
    float a0, a1, a2, a3;
    {
      f16x4 v = H4[(size_t)node * 32 + li];
      float wv = 0.5f * dn * dn;
      a0 = wv*(float)v[0]; a1 = wv*(float)v[1]; a2 = wv*(float)v[2]; a3 = wv*(float)v[3];
    }
    int dl = d < 64 ? d : 64;
    int j = 0;
    for (; j + 7 < dl; j += 8) {
      int i0 = __shfl(sidx, j + half, 64),     i1 = __shfl(sidx, j + 2 + half, 64);
      int i2 = __shfl(sidx, j + 4 + half, 64), i3 = __shfl(sidx, j + 6 + half, 64);
      float w0 = __shfl(swt, j + half, 64),     w1 = __shfl(swt, j + 2 + half, 64);
      float w2 = __shfl(swt, j + 4 + half, 64), w3 = __shfl(swt, j + 6 + half, 64);
      f16x4 v0 = H4[(size_t)i0 * 32 + li];
      f16x4 v1 = H4[(size_t)i1 * 32 + li];
      f16x4 v2 = H4[(size_t)i2 * 32 + li];
      f16x4 v3 = H4[(size_t)i3 * 32 + li];
      a0 += w0*(float)v0[0] + w1*(float)v1[0] + w2*(float)v2[0] + w3*(float)v3[0];
      a1 += w0*(float)v0[1] + w1*(float)v1[1] + w2*(float)v2[1] + w3*(float)v3[1];
      a2 += w0*(float)v0[2] + w1*(float)v1[2] + w2*(float)v2[2] + w3*(float)v3[2];
      a3 += w0*(float)v0[3] + w1*(float)v1[3] + w2*(float)v2[3] + w3*(float)v3[3];
    }
    for (; j + 1 < dl; j += 2) {
      int ii = __shfl(sidx, j + half, 64);
      float ww = __shfl(swt, j + half, 64);
      f16x4 v = H4[(size_t)ii * 32 + li];
      a0 += ww*(float)v[0]; a1 += ww*(float)v[1]; a2 += ww*(float)v[2]; a3 += ww*(float)v[3];
    }
    if (j < dl) {   // last odd row: both halves, half weight
      int ii = __shfl(sidx, j, 64);
      float ww = 0.5f * __shfl(swt, j, 64);
      f16x4 v = H4[(size_t)ii * 32 + li];
      a0 += ww*(float)v[0]; a1 += ww*(float)v[1]; a2 += ww*(float)v[2]; a3 += ww*(float)v[3];
    }
    for (int e = rs + 64; e < re; e++) {   // rare deg>64 tail: both halves, half weight
      int s = csr[e]; float wv = 0.5f * csrw[e];
      f16x4 v = H4[(size_t)s * 32 + li];
      a0 += wv*(float)v[0]; a1 += wv*(float)v[1]; a2 += wv*(float)v[2]; a3 += wv*(float)v[3];
    }
    a0 += __shfl_xor(a0, 32, 64); a1 += __shfl_xor(a1, 32, 64);
    a2 += __shfl_xor(a2, 32, 64); a3 += __shfl_xor(a3, 32, 64);
    if (half == 0) {
      float4 bv = ((const float4*)bias)[li];
      o0 = a0 + bv.x; o1 = a1 + bv.y; o2 = a2 + bv.z; o3 = a3 + bv.w;
      if (leaky_flag) { o0 = lrelu(o0,0.01f); o1 = lrelu(o1,0.01f); o2 = lrelu(o2,0.01f); o3 = lrelu(o3,0.01f); }
      if (xout4) xout4[(size_t)node * 32 + li] = make_float4(o0, o1, o2, o3);
      if (y4) { f16x4 o = { (f16)o0, (f16)o1, (f16)o2, (f16)o3 }; y4[(size_t)node * 32 + li] = o; }
    }
  }
  if (psum) {
    if (half == 0) {
      s1[w][4*li+0]=o0; s1[w][4*li+1]=o1; s1[w][4*li+2]=o2; s1[w][4*li+3]=o3;
      s2[w][4*li+0]=o0*o0; s2[w][4*li+1]=o1*o1; s2[w][4*li+2]=o2*o2; s2[w][4*li+3]=o3*o3;
    }
    __syncthreads();
    int t = threadIdx.x;
    if (t < 128) {
      float S = s1[0][t] + s1[1][t] + s1[2][t] + s1[3][t];
      float Q = s2[0][t] + s2[1][t] + s2[2][t] + s2[3][t];
      int slot = blockIdx.x & 127;
      atomicAdd(&psum[slot * 128 + t], S);
      atomicAdd(&psumsq[slot * 128 + t], Q);
    }
  }
}

// ---------------- GAT aggregation: 2 rows/instr + fused softmax/stats ----------
__global__ __launch_bounds__(256) void k_gat_agg16(const f16x4* __restrict__ H4,
    const float* __restrict__ als, const float* __restrict__ ald,
    const int* __restrict__ row_ptr, const int* __restrict__ csr,
    const float* __restrict__ bias, f16x4* __restrict__ y4, int n,
    float* __restrict__ psum, float* __restrict__ psumsq) {
  int w = threadIdx.x >> 6;
  int node = blockIdx.x * 4 + w;
  int lane = threadIdx.x & 63;
  int half = lane >> 5, li = lane & 31;
  __shared__ float s1[4][128], s2[4][128];
  float o0=0.f,o1=0.f,o2=0.f,o3=0.f;
  if (node < n) {
    int rs = row_ptr[node], re = row_ptr[node + 1];
    int d = re - rs;
    float aldn = ald[node];
    float e_self = lrelu(als[node] + aldn, 0.2f);
    float a0, a1, a2, a3, sm;
    if (d <= 64) {
      int sidx = (lane < d) ? csr[rs + lane] : 0;
      float e_k = (lane < d) ? lrelu(als[sidx] + aldn, 0.2f) : -3.4e38f;
      float tmx = e_k;
      for (int off = 1; off < 64; off <<= 1) tmx = fmaxf(tmx, __shfl_xor(tmx, off, 64));
      float mx = fmaxf(e_self, tmx);
      float g_k = (lane < d) ? __expf(e_k - mx) : 0.f;
      float tsm = g_k;
      for (int off = 1; off < 64; off <<= 1) tsm += __shfl_xor(tsm, off, 64);
      float ws = __expf(e_self - mx);
      sm = tsm + ws;
      {
        f16x4 v = H4[(size_t)node * 32 + li];
        float wv = 0.5f * ws;
        a0 = wv*(float)v[0]; a1 = wv*(float)v[1]; a2 = wv*(float)v[2]; a3 = wv*(float)v[3];
      }
      int j = 0;
      for (; j + 7 < d; j += 8) {
        int i0 = __shfl(sidx, j + half, 64),     i1 = __shfl(sidx, j + 2 + half, 64);
        int i2 = __shfl(sidx, j + 4 + half, 64), i3 = __shfl(sidx, j + 6 + half, 64);
        float g0 = __shfl(g_k, j + half, 64),     g1 = __shfl(g_k, j + 2 + half, 64);
        float g2 = __shfl(g_k, j + 4 + half, 64), g3 = __shfl(g_k, j + 6 + half, 64);
        f16x4 v0 = H4[(size_t)i0 * 32 + li];
        f16x4 v1 = H4[(size_t)i1 * 32 + li];
        f16x4 v2 = H4[(size_t)i2 * 32 + li];
        f16x4 v3 = H4[(size_t)i3 * 32 + li];
        a0 += g0*(float)v0[0] + g1*(float)v1[0] + g2*(float)v2[0] + g3*(float)v3[0];
        a1 += g0*(float)v0[1] + g1*(float)v1[1] + g2*(float)v2[1] + g3*(float)v3[1];
        a2 += g0*(float)v0[2] + g1*(float)v1[2] + g2*(float)v2[2] + g3*(float)v3[2];
        a3 += g0*(float)v0[3] + g1*(float)v1[3] + g2*(float)v2[3] + g3*(float)v3[3];
      }
      for (; j + 1 < d; j += 2) {
        int ii = __shfl(sidx, j + half, 64);
        float gg = __shfl(g_k, j + half, 64);
        f16x4 v = H4[(size_t)ii * 32 + li];
        a0 += gg*(float)v[0]; a1 += gg*(float)v[1]; a2 += gg*(float)v[2]; a3 += gg*(float)v[3];
      }
      if (j < d) {
        int ii = __shfl(sidx, j, 64);
        float gg = 0.5f * __shfl(g_k, j, 64);
        f16x4 v = H4[(size_t)ii * 32 + li];
        a0 += gg*(float)v[0]; a1 += gg*(float)v[1]; a2 += gg*(float)v[2]; a3 += gg*(float)v[3];
      }
    } else {   // rare deg>64 slow path
      float mx = e_self;
      for (int i = rs + lane; i < re; i += 64) mx = fmaxf(mx, lrelu(als[csr[i]] + aldn, 0.2f));
      for (int off = 1; off < 64; off <<= 1) mx = fmaxf(mx, __shfl_xor(mx, off, 64));
      float ws = __expf(e_self - mx);
      sm = ws;
      {
        f16x4 v = H4[(size_t)node * 32 + li];
        float wv = 0.5f * ws;
        a0 = wv*(float)v[0]; a1 = wv*(float)v[1]; a2 = wv*(float)v[2]; a3 = wv*(float)v[3];
      }
      for (int e = rs; e < re; e++) {
        int s = csr[e];
        float g = __expf(lrelu(als[s] + aldn, 0.2f) - mx);
        sm += g;
        float gg = 0.5f * g;
        f16x4 v = H4[(size_t)s * 32 + li];
        a0 += gg*(float)v[0]; a1 += gg*(float)v[1]; a2 += gg*(float)v[2]; a3 += gg*(float)v[3];
      }
    }
    a0 += __shfl_xor(a0, 32, 64); a1 += __shfl_xor(a1, 32, 64);
    a2 += __shfl_xor(a2, 32, 64); a3 += __shfl_xor(a3, 32, 64);
    if (half == 0) {
      float inv_s = 1.f / sm;
      float4 bv = ((const float4*)bias)[li];
      o0 = a0 * inv_s + bv.x; o1 = a1 * inv_s + bv.y;
      o2 = a2 * inv_s + bv.z; o3 = a3 * inv_s + bv.w;
      f16x4 o = { (f16)o0, (f16)o1, (f16)o2, (f16)o3 };
      y4[(size_t)node * 32 + li] = o;
    }
  }
  if (half == 0) {
    s1[w][4*li+0]=o0; s1[w][4*li+1]=o1; s1[w][4*li+2]=o2; s1[w][4*li+3]=o3;
    s2[w][4*li+0]=o0*o0; s2[w][4*li+1]=o1*o1; s2[w][4*li+2]=o2*o2; s2[w][4*li+3]=o3*o3;
  }
  __syncthreads();
  int t = threadIdx.x;
  if (t < 128) {
    float S = s1[0][t] + s1[1][t] + s1[2][t] + s1[3][t];
    float Q = s2[0][t] + s2[1][t] + s2[2][t] + s2[3][t];
    int slot = blockIdx.x & 127;
    atomicAdd(&psum[slot * 128 + t], S);
    atomicAdd(&psumsq[slot * 128 + t], Q);
  }
}

// ---------------- GraphNorm stats ----------------
__global__ __launch_bounds__(256) void k_stats(const float* __restrict__ psum,
    const float* __restrict__ psumsq, const float* __restrict__ w,
    const float* __restrict__ bb, const float* __restrict__ ms,
    float* __restrict__ scaleA, float* __restrict__ shiftA, int n) {
  int t = threadIdx.x, c = t & 127, half = t >> 7;
  float S = 0.f, Q = 0.f;
  for (int s = half; s < 128; s += 2) { S += psum[s * 128 + c]; Q += psumsq[s * 128 + c]; }
  __shared__ float sh[256], sq[256];
  sh[t] = S; sq[t] = Q;
  __syncthreads();
  if (half == 0) {
    double Sd = (double)sh[c] + (double)sh[c + 128];
    double Qd = (double)sq[c] + (double)sq[c + 128];
    double invn = 1.0 / (double)n;
    double mean = Sd * invn;
    double mt = (double)ms[c] * mean;
    double var = Qd * invn - 2.0 * mt * mean + mt * mt;
    float rstd = rsqrtf((float)var + 1e-5f);
    float sc = w[c] * rstd;
    scaleA[c] = sc;
    shiftA[c] = bb[c] - sc * (float)mt;
  }
}

// ---------------- Output head: dot1 with fused final residual ----------------
__global__ __launch_bounds__(256) void k_dot1(const float2* __restrict__ x2,
    const f16x2* __restrict__ y2, const float* __restrict__ scaleA,
    const float* __restrict__ shiftA, const float* __restrict__ wv,
    float* __restrict__ o, int n) {
  int node = blockIdx.x * 4 + (threadIdx.x >> 6);
  int lane = threadIdx.x & 63;
  if (node >= n) return;
  float2 xv = x2[(size_t)node * 64 + lane];
  f16x2 yv = y2[(size_t)node * 64 + lane];
  float2 sc = ((const float2*)scaleA)[lane];
  float2 sh = ((const float2*)shiftA)[lane];
  float a = xv.x + lrelu(sc.x * (float)yv[0] + sh.x, 0.01f);
  float b = xv.y + lrelu(sc.y * (float)yv[1] + sh.y, 0.01f);
  float2 v1 = ((const float2*)wv)[lane];
  float s1 = a * v1.x + b * v1.y;
  for (int off = 32; off > 0; off >>= 1) s1 += __shfl_down(s1, off, 64);
  if (lane == 0) o[node] = s1;
}

__global__ __launch_bounds__(256) void k_scalar_agg(const float* __restrict__ xsv,
    const float* __restrict__ dinv, const int* __restrict__ row_ptr,
    const int* __restrict__ csr, const float* __restrict__ csrw,
    const float* __restrict__ b_out, float* __restrict__ xout, int n) {
  int i = blockIdx.x * 256 + threadIdx.x;
  if (i >= n) return;
  float dn = dinv[i];
  float acc = dn * dn * xsv[i];
  int re = row_ptr[i + 1];
  for (int e = row_ptr[i]; e < re; e++)
    acc += csrw[e] * xsv[csr[e]];
  xout[i] = lrelu(acc + b_out[0], 0.01f);
}

__global__ __launch_bounds__(256) void k_fc1(const float* __restrict__ xout,
    const float* __restrict__ fw, float* __restrict__ pfc, int n, int chunk) {
  int b = blockIdx.x, t = threadIdx.x;
  int c = t & 127, half = t >> 7;
  int s0 = b * chunk;
  int s1 = s0 + chunk; if (s1 > n) s1 = n;
  float s = 0.f;
  for (int i = s0 + half; i < s1; i += 2) s += xout[i] * fw[(size_t)i * 128 + c];
  __shared__ float sh[256];
  sh[t] = s; __syncthreads();
  if (half == 0) pfc[b * 128 + c] = sh[c] + sh[c + 128];
}

__global__ __launch_bounds__(128) void k_final(const float* __restrict__ pfc,
    const float* __restrict__ b1, const float* __restrict__ fw2,
    const float* __restrict__ b2, float* __restrict__ out) {
  int c = threadIdx.x;
  float s = 0.f;
  for (int b = 0; b < 128; b++) s += pfc[b * 128 + c];
  float hv = lrelu(s + b1[c], 0.01f);
  __shared__ float h1[128];
  h1[c] = hv; __syncthreads();
  float o = b2[c];
  for (int j = 0; j < 128; j++) o += h1[j] * fw2[j * 128 + c];
  out[c] = o;
}

// ---------------- host ----------------
extern "C" void kernel_launch(void* const* d_in, const int* in_sizes, int n_in,
                              void* d_out, int out_size, void* d_ws, size_t ws_size,
                              hipStream_t stream) {
  const int* poi      = (const int*)d_in[0];
  const float* dist   = (const float*)d_in[1];
  const int* ei       = (const int*)d_in[2];
  const float* emb    = (const float*)d_in[3];
  const float* W_in   = (const float*)d_in[4];
  const float* b_in   = (const float*)d_in[5];
  const float* gcn_W  = (const float*)d_in[6];
  const float* gcn_b  = (const float*)d_in[7];
  const float* norm_w = (const float*)d_in[8];
  const float* norm_b = (const float*)d_in[9];
  const float* norm_ms= (const float*)d_in[10];
  const float* gat_W  = (const float*)d_in[11];
  const float* gat_as = (const float*)d_in[12];
  const float* gat_ad = (const float*)d_in[13];
  const float* gat_b  = (const float*)d_in[14];
  const float* W_out  = (const float*)d_in[15];
  const float* b_out  = (const float*)d_in[16];
  const float* fc1_W  = (const float*)d_in[17];
  const float* fc1_b  = (const float*)d_in[18];
  const float* fc2_W  = (const float*)d_in[19];
  const float* fc2_b  = (const float*)d_in[20];

  const int N   = in_sizes[0] / 32;
  const int E   = in_sizes[2] / 2;
  const int POI = in_sizes[3] / 128;
  const int* srcp = ei;
  const int* dstp = ei + E;
  float* out = (float*)d_out;

  char* p = (char*)d_ws;
  auto alloc = [&](size_t bytes) { char* r = p; p += (bytes + 255) & ~(size_t)255; return r; };
  float* x   = (float*)alloc((size_t)N * 128 * 4);
  f16* h16   = (f16*)alloc((size_t)N * 128 * 2);
  size_t Rneed = (size_t)POI * 128 * 2;              // f16 emb table
  size_t Ry    = (size_t)N * 128 * 2;                // y f16 (reused after embed)
  char* R = alloc(Rneed > Ry ? Rneed : Ry);
  f16* ehalf = (f16*)R;
  f16* y16   = (f16*)R;
  const int KBIN = 4128 / 8;
  f16* wih = (f16*)alloc((size_t)KBIN * 128 * 8 * 2);
  f16* wsh = (f16*)alloc((size_t)8 * 16384 * 2);
  f16* wsl = (f16*)alloc((size_t)8 * 16384 * 2);
  float* dinv   = (float*)alloc((size_t)N * 4);
  float* als    = (float*)alloc((size_t)N * 4);
  float* ald    = (float*)alloc((size_t)N * 4);
  float* xsv    = (float*)alloc((size_t)N * 4);
  float* xout   = (float*)alloc((size_t)N * 4);
  float* statsbuf = (float*)alloc((size_t)32 * 16384 * 4);
  float* pfc    = (float*)alloc(128 * 128 * 4);
  float* scaleA = (float*)alloc(128 * 4);
  float* shiftA = (float*)alloc(128 * 4);
  int* deg     = (int*)alloc((size_t)N * 2 * 4);   // deg+fill contiguous: one memset
  int* fill    = deg + N;
  int* row_ptr = (int*)alloc(((size_t)N + 1) * 4);
  int* csr     = (int*)alloc((size_t)E * 4);
  float* csrw  = (float*)alloc((size_t)E * 4);
  int* bsum    = (int*)alloc(64 * 4);

  const int chunk = (N + 127) / 128;
  const int gblocks = (N + 63) / 64;
  const int eblocks = (E + 255) / 256;
  const int nwb = (N + 3) / 4;
  const int nb1024 = (N + 1023) / 1024;

  hipMemsetAsync(deg, 0, sizeof(int) * 2 * (size_t)N, stream);
  hipMemsetAsync(statsbuf, 0, (size_t)32 * 16384 * 4, stream);
  k_deg<<<eblocks, 256, 0, stream>>>(dstp, deg, E);
  k_scan1<<<nb1024, 1024, 0, stream>>>(deg, row_ptr, bsum, dinv, N);
  k_scan2<<<1, 64, 0, stream>>>(bsum, nb1024);
  k_scan3<<<(N + 255) / 256, 256, 0, stream>>>(row_ptr, bsum, N);
  k_fill<<<eblocks, 256, 0, stream>>>(srcp, dstp, row_ptr, dinv, fill, csr, csrw, E);

  int et4 = POI * 128 / 4;
  k_conv_emb<<<(et4 + 255) / 256, 256, 0, stream>>>(emb, ehalf, et4);
  k_pack_w<<<(KBIN * 128 + 255) / 256, 256, 0, stream>>>(W_in, wih, KBIN);
  k_pack_w8<<<dim3(8, 8), 256, 0, stream>>>(gcn_W, gat_W, wsh, wsl);

  // input layer: embed GEMM -> input GCN agg (writes x fp32, leaky)
  k_mfma_embed<<<gblocks, 512, 0, stream>>>(poi, dist, ehalf, wih, h16, N);
  k_gcn_agg16<<<nwb, 256, 0, stream>>>((const f16x4*)h16, dinv, row_ptr, csr, csrw, b_in,
                                       (float4*)x, (f16x4*)nullptr, N, 1, nullptr, nullptr);

  for (int l = 0; l < 4; l++) {
    const f16* gh = wsh + (size_t)l * 16384;
    const f16* gl = wsl + (size_t)l * 16384;
    const f16* th = wsh + (size_t)(4 + l) * 16384;
    const f16* tl = wsl + (size_t)(4 + l) * 16384;
    float* ps0 = statsbuf + (size_t)(4 * l) * 16384;
    float* pq0 = ps0 + 16384;
    float* ps1 = ps0 + 2 * 16384;
    float* pq1 = ps0 + 3 * 16384;
    // GCN sub-unit: lin consumes previous stage's y (null for l==0)
    k_mfma_lin<<<gblocks, 256, 0, stream>>>(x, (l == 0) ? (const f16*)nullptr : y16,
                                            scaleA, shiftA, gh, gl, h16, N,
                                            (const float*)nullptr, (const float*)nullptr,
                                            (float*)nullptr, (float*)nullptr);
    k_gcn_agg16<<<nwb, 256, 0, stream>>>((const f16x4*)h16, dinv, row_ptr, csr, csrw,
                                         gcn_b + l * 128, (float4*)nullptr, (f16x4*)y16,
                                         N, 0, ps0, pq0);
    k_stats<<<1, 256, 0, stream>>>(ps0, pq0, norm_w + l * 128, norm_b + l * 128,
                                   norm_ms + l * 128, scaleA, shiftA, N);
    // GAT sub-unit: lin applies GCN residual, computes a-dots in epilogue
    k_mfma_lin<<<gblocks, 256, 0, stream>>>(x, y16, scaleA, shiftA, th, tl, h16, N,
                                            gat_as + l * 128, gat_ad + l * 128, als, ald);
    k_gat_agg16<<<nwb, 256, 0, stream>>>((const f16x4*)h16, als, ald, row_ptr, csr,
                                         gat_b + l * 128, (f16x4*)y16, N, ps1, pq1);
    k_stats<<<1, 256, 0, stream>>>(ps1, pq1, norm_w + l * 128, norm_b + l * 128,
                                   norm_ms + l * 128, scaleA, shiftA, N);
  }

  // output head: dot1 fuses the final residual
  k_dot1<<<nwb, 256, 0, stream>>>((const float2*)x, (const f16x2*)y16, scaleA, shiftA,
                                  W_out, xsv, N);
  k_scalar_agg<<<(N + 255) / 256, 256, 0, stream>>>(xsv, dinv, row_ptr, csr, csrw, b_out, xout, N);
  k_fc1<<<128, 256, 0, stream>>>(xout, fc1_W, pfc, N, chunk);
  k_final<<<1, 128, 0, stream>>>(pfc, fc1_b, fc2_W, fc2_b, out);
}